// Round 5
// baseline (90.054 us; speedup 1.0000x reference)
//
#include <hip/hip_runtime.h>

#define NUM_POINTS 2048
#define FEAT 512
#define BATCH 32
#define POS_PER_BLOCK 2   // 2 positions x 2 M-split waves = 4 waves/block

using v8s = __attribute__((ext_vector_type(8))) short;
using v4f = __attribute__((ext_vector_type(4))) float;

// fp32 -> bf16 round-to-nearest-even
static __device__ __forceinline__ short f2bf(float x) {
  unsigned u = __float_as_uint(x);
  u += 0x7FFFu + ((u >> 16) & 1u);
  return (short)(u >> 16);
}

static __device__ __forceinline__ v8s cvt8(const float* p) {
  float4 f0 = *(const float4*)(p);
  float4 f1 = *(const float4*)(p + 4);
  v8s r;
  r[0] = f2bf(f0.x); r[1] = f2bf(f0.y); r[2] = f2bf(f0.z); r[3] = f2bf(f0.w);
  r[4] = f2bf(f1.x); r[5] = f2bf(f1.y); r[6] = f2bf(f1.z); r[7] = f2bf(f1.w);
  return r;
}

// Pack glf (fp32 [32][512]) into bf16 MFMA B-fragments in ws (proven R1/R3).
// lane l holds B[k = ks*32 + (l>>4)*8 + j][col = nt*16 + (l&15)], j=0..7
__global__ void build_bfrag(const float* __restrict__ glf, short* __restrict__ frag) {
  int i = blockIdx.x * 256 + threadIdx.x;  // 0..16383
  int j = i & 7;
  int l = (i >> 3) & 63;
  int nt = (i >> 9) & 1;
  int ks = i >> 10;
  int b = nt * 16 + (l & 15);
  int k = ks * 32 + ((l >> 4) << 3) + j;
  frag[i] = f2bf(glf[b * FEAT + k]);
}

// DIAGNOSTIC build of R3's split-M kernel: the W1-streaming K-loop runs 4x.
// Reps 0-2: identical instruction mix, results kept live via asm, discarded.
// Rep 3: the real pass (bit-identical result to R3). Purpose: push this
// dispatch above the harness's 75us fill kernels so rocprof shows OUR
// counters (FETCH_SIZE, hbm_gbps, MfmaUtil, VALUBusy, Occupancy).
__global__ void __launch_bounds__(256) fcdec_main(
    const float* __restrict__ W1, const float* __restrict__ b1,
    const float* __restrict__ W2, const float* __restrict__ b2,
    const float* __restrict__ W3, const float* __restrict__ b3,
    const short* __restrict__ bfrag, float* __restrict__ out) {
  __shared__ float h1s[POS_PER_BLOCK][32][33];  // 8.4 KB

  const int t = threadIdx.x;
  const int w = t >> 6;
  const int l = t & 63;
  const int lp = w >> 1;            // position within block
  const int mt = w & 1;             // M-split
  const int p = blockIdx.x * POS_PER_BLOCK + lp;
  const int lrow = l & 15;
  const int lk = (l >> 4) << 3;     // 0,8,16,24

  // Opaque runtime zero (defeats cross-rep load CSE; value is 0).
  int zero;
  asm volatile("v_mov_b32 %0, 0" : "=v"(zero));

  const float* A0 = W1 + ((size_t)p * 32u + mt * 16 + lrow) * FEAT + lk;

  v4f accKeep[2];
  #pragma unroll 1
  for (int rep = 0; rep < 4; ++rep) {
    const float* Ar = A0 + zero * (rep + 1);   // provably-distinct SSA address
    v4f acc[2] = {};
    #pragma unroll 4
    for (int ks = 0; ks < 16; ++ks) {
      v8s a = cvt8(Ar + ks * 32);
      v8s bv0 = *(const v8s*)(bfrag + (((ks * 2 + 0) * 64 + l) << 3));
      v8s bv1 = *(const v8s*)(bfrag + (((ks * 2 + 1) * 64 + l) << 3));
      acc[0] = __builtin_amdgcn_mfma_f32_16x16x32_bf16(a, bv0, acc[0], 0, 0, 0);
      acc[1] = __builtin_amdgcn_mfma_f32_16x16x32_bf16(a, bv1, acc[1], 0, 0, 0);
    }
    if (rep == 3) {
      accKeep[0] = acc[0];
      accKeep[1] = acc[1];
    } else {
      // keep the whole load->cvt->MFMA chain live, then discard
      asm volatile("" :: "v"(acc[0][0]), "v"(acc[0][1]), "v"(acc[0][2]), "v"(acc[0][3]),
                         "v"(acc[1][0]), "v"(acc[1][1]), "v"(acc[1][2]), "v"(acc[1][3]));
    }
  }

  // Epilogue: h1 = accKeep + b1 -> LDS. C/D: lane l holds C[row=(l>>4)*4+r][col=l&15]
  #pragma unroll
  for (int nt = 0; nt < 2; ++nt)
    #pragma unroll
    for (int r = 0; r < 4; ++r) {
      int o = mt * 16 + ((l >> 4) << 2) + r;
      int b = nt * 16 + (l & 15);
      h1s[lp][o][b] = accKeep[nt][r] + b1[p * 32 + o];
    }
  __syncthreads();

  // Layers 2+3 fp32: one thread per (position-in-block, batch)
  if (t < POS_PER_BLOCK * BATCH) {
    const int tp = t >> 5;
    const int b = t & 31;
    const int pg = blockIdx.x * POS_PER_BLOCK + tp;
    float h2[8];
    #pragma unroll
    for (int o8 = 0; o8 < 8; ++o8) {
      float s = b2[pg * 8 + o8];
      const float* w2 = W2 + (size_t)(pg * 8 + o8) * 32;
      #pragma unroll
      for (int i = 0; i < 32; ++i) s += w2[i] * h1s[tp][i][b];
      h2[o8] = s;
    }
    #pragma unroll
    for (int c = 0; c < 3; ++c) {
      float s = b3[pg * 3 + c];
      const float* w3 = W3 + (size_t)(pg * 3 + c) * 8;
      #pragma unroll
      for (int j = 0; j < 8; ++j) s += w3[j] * h2[j];
      out[(size_t)(b * 3 + c) * NUM_POINTS + pg] = s;
    }
  }
}

extern "C" void kernel_launch(void* const* d_in, const int* in_sizes, int n_in,
                              void* d_out, int out_size, void* d_ws, size_t ws_size,
                              hipStream_t stream) {
  const float* glf = (const float*)d_in[0];
  const float* W1  = (const float*)d_in[1];
  const float* b1  = (const float*)d_in[2];
  const float* W2  = (const float*)d_in[3];
  const float* b2  = (const float*)d_in[4];
  const float* W3  = (const float*)d_in[5];
  const float* b3  = (const float*)d_in[6];
  float* out = (float*)d_out;
  short* frag = (short*)d_ws;  // 32 KB of bf16 B-fragments

  hipLaunchKernelGGL(build_bfrag, dim3(64), dim3(256), 0, stream, glf, frag);
  hipLaunchKernelGGL(fcdec_main, dim3(NUM_POINTS / POS_PER_BLOCK), dim3(256), 0, stream,
                     W1, b1, W2, b2, W3, b3, frag, out);
}

// Round 6
// 31.503 us; speedup vs baseline: 2.8586x; 2.8586x over previous
//
#include <hip/hip_runtime.h>

#define NUM_POINTS 2048
#define FEAT 512
#define BATCH 32
#define POS_PER_BLOCK 2   // 2 positions x 2 M-split waves = 4 waves/block

using v8s = __attribute__((ext_vector_type(8))) short;
using v4f = __attribute__((ext_vector_type(4))) float;

// fp32 -> bf16 round-to-nearest-even
static __device__ __forceinline__ short f2bf(float x) {
  unsigned u = __float_as_uint(x);
  u += 0x7FFFu + ((u >> 16) & 1u);
  return (short)(u >> 16);
}

// Single fused kernel. Per block: build bf16 B-fragments in LDS from glf
// (hidden under the first A-prefetch group), then split-M MFMA main loop
// with an explicit 8-deep rotating A-prefetch (16 dwordx4 in flight), then
// the 32->8->3 tail. h1s aliases the bfrag LDS region (barrier-separated)
// to keep LDS at 32KB -> 4 blocks/CU.
__global__ void __launch_bounds__(256, 4) fcdec_fused(
    const float* __restrict__ glf,
    const float* __restrict__ W1, const float* __restrict__ b1,
    const float* __restrict__ W2, const float* __restrict__ b2,
    const float* __restrict__ W3, const float* __restrict__ b3,
    float* __restrict__ out) {
  __shared__ char smem[32768];
  short* bfrag = (short*)smem;                       // [16 ks][2 nt][64 l][8 j]
  float (*h1s)[32][33] = (float (*)[32][33])smem;    // aliases bfrag (after barrier)

  const int t = threadIdx.x;
  const int w = t >> 6;
  const int l = t & 63;
  const int lp = w >> 1;            // position within block
  const int mt = w & 1;             // M-split
  const int p = blockIdx.x * POS_PER_BLOCK + lp;
  const int lrow = l & 15;
  const int lk = (l >> 4) << 3;     // 0,8,16,24

  const float* A0 = W1 + ((size_t)p * 32u + mt * 16 + lrow) * FEAT + lk;

  // ---- Issue A-prefetch group 0 (ks 0..7): 16 dwordx4 in flight ----
  float4 fa0[8], fa1[8];
  #pragma unroll
  for (int kk = 0; kk < 8; ++kk) {
    fa0[kk] = *(const float4*)(A0 + kk * 32);
    fa1[kk] = *(const float4*)(A0 + kk * 32 + 4);
  }

  // ---- Build B fragments in LDS from glf (overlaps A latency) ----
  // frag layout: lane l holds B[k=ks*32+(l>>4)*8+j][col=nt*16+(l&15)]
  // element (b,k): nt=b>>4, ll=((k>>3)&3)*16+(b&15), ks=k>>5, j=k&7
  #pragma unroll
  for (int rep = 0; rep < 16; ++rep) {
    int c = rep * 256 + t;          // float4 chunk id, coalesced in k
    int b = c >> 7;
    int k0 = (c & 127) << 2;
    float4 g = *(const float4*)(glf + b * FEAT + k0);
    int ks = k0 >> 5;
    int gsel = (k0 >> 3) & 3;
    int j0 = k0 & 7;                // 0 or 4
    int nt = b >> 4;
    int ll = gsel * 16 + (b & 15);
    short* dst = bfrag + (((ks * 2 + nt) * 64 + ll) << 3) + j0;
    dst[0] = f2bf(g.x); dst[1] = f2bf(g.y); dst[2] = f2bf(g.z); dst[3] = f2bf(g.w);
  }
  __syncthreads();

  // ---- Main loop: K=512, 8-deep rotating prefetch, 2 MFMA/ks ----
  v4f acc0 = {}, acc1 = {};
  #pragma unroll
  for (int ks = 0; ks < 16; ++ks) {
    float4 c0 = fa0[ks & 7];
    float4 c1 = fa1[ks & 7];
    if (ks < 8) {                   // static under full unroll
      fa0[ks] = *(const float4*)(A0 + (ks + 8) * 32);
      fa1[ks] = *(const float4*)(A0 + (ks + 8) * 32 + 4);
    }
    v8s a;
    a[0] = f2bf(c0.x); a[1] = f2bf(c0.y); a[2] = f2bf(c0.z); a[3] = f2bf(c0.w);
    a[4] = f2bf(c1.x); a[5] = f2bf(c1.y); a[6] = f2bf(c1.z); a[7] = f2bf(c1.w);
    v8s bv0 = *(const v8s*)(bfrag + (((ks * 2 + 0) * 64 + l) << 3));
    v8s bv1 = *(const v8s*)(bfrag + (((ks * 2 + 1) * 64 + l) << 3));
    acc0 = __builtin_amdgcn_mfma_f32_16x16x32_bf16(a, bv0, acc0, 0, 0, 0);
    acc1 = __builtin_amdgcn_mfma_f32_16x16x32_bf16(a, bv1, acc1, 0, 0, 0);
  }

  __syncthreads();   // all bfrag reads done before h1s overwrites the region

  // ---- h1 = acc + b1 -> LDS. C/D: lane l holds C[row=(l>>4)*4+r][col=l&15]
  #pragma unroll
  for (int r = 0; r < 4; ++r) {
    const int o = mt * 16 + ((l >> 4) << 2) + r;
    const float bb = b1[p * 32 + o];
    h1s[lp][o][lrow] = acc0[r] + bb;
    h1s[lp][o][16 + lrow] = acc1[r] + bb;
  }
  __syncthreads();

  // ---- Layers 2+3 fp32: one thread per (position-in-block, batch) ----
  if (t < POS_PER_BLOCK * BATCH) {
    const int tp = t >> 5;
    const int b = t & 31;
    const int pg = blockIdx.x * POS_PER_BLOCK + tp;
    float h2[8];
    #pragma unroll
    for (int o8 = 0; o8 < 8; ++o8) {
      float s = b2[pg * 8 + o8];
      const float* w2 = W2 + (size_t)(pg * 8 + o8) * 32;
      #pragma unroll
      for (int i = 0; i < 32; ++i) s += w2[i] * h1s[tp][i][b];
      h2[o8] = s;
    }
    #pragma unroll
    for (int c = 0; c < 3; ++c) {
      float s = b3[pg * 3 + c];
      const float* w3 = W3 + (size_t)(pg * 3 + c) * 8;
      #pragma unroll
      for (int j = 0; j < 8; ++j) s += w3[j] * h2[j];
      out[(size_t)(b * 3 + c) * NUM_POINTS + pg] = s;
    }
  }
}

extern "C" void kernel_launch(void* const* d_in, const int* in_sizes, int n_in,
                              void* d_out, int out_size, void* d_ws, size_t ws_size,
                              hipStream_t stream) {
  const float* glf = (const float*)d_in[0];
  const float* W1  = (const float*)d_in[1];
  const float* b1  = (const float*)d_in[2];
  const float* W2  = (const float*)d_in[3];
  const float* b2  = (const float*)d_in[4];
  const float* W3  = (const float*)d_in[5];
  const float* b3  = (const float*)d_in[6];
  float* out = (float*)d_out;

  hipLaunchKernelGGL(fcdec_fused, dim3(NUM_POINTS / POS_PER_BLOCK), dim3(256), 0, stream,
                     glf, W1, b1, W2, b2, W3, b3, out);
}